// Round 6
// baseline (152.840 us; speedup 1.0000x reference)
//
#include <hip/hip_runtime.h>
#include <math.h>

#define EPSF   1e-8f
#define NV4    2645760   // 512*6890*3 / 4
#define PER_B  20670     // 6890*3

// One fused kernel. Side roles get low bids (scheduled first -> overlap with
// the vertex stream). ws[bid] = each block's partial (double); written
// unconditionally -> no init/memset needed.
#define S_PROC   0      // 8 blocks  -> pa      (64 active threads each)
#define S_NV     8      // 2 blocks  -> nvalid
#define S_BETA   10     // 20 blocks
#define S_KP2D   30     // 48 blocks
#define S_KP3D   78     // 48 blocks
#define S_POSE   126    // 108 blocks (27648 float4)
#define NSIDE    234
#define NVBLK    1292   // vertex chunks of 2048 float4
#define NBLK     (NSIDE + NVBLK)   // 1526

__device__ __forceinline__ float frcp(float x)  { return __builtin_amdgcn_rcpf(x); }
__device__ __forceinline__ float frsq(float x)  { return __builtin_amdgcn_rsqf(x); }
__device__ __forceinline__ float fsqrt(float x) { return __builtin_amdgcn_sqrtf(x); }

__device__ __forceinline__ void block_sum_store(float v, double* dst) {
  #pragma unroll
  for (int off = 32; off > 0; off >>= 1) v += __shfl_down(v, off);
  __shared__ float red[4];
  const int lane = threadIdx.x & 63;
  const int wid  = threadIdx.x >> 6;
  if (lane == 0) red[wid] = v;
  __syncthreads();
  if (threadIdx.x == 0) *dst = (double)(red[0] + red[1] + red[2] + red[3]);
}

// ---------------- Jacobi helpers for procrustes ----------------
template<int P, int Q>
__device__ __forceinline__ void jrot(float A[3][3], float Vv[3][3]) {
  float apq = A[P][Q];
  if (fabsf(apq) < 1e-20f) return;
  float tau = (A[Q][Q] - A[P][P]) * 0.5f * frcp(apq);
  float t   = copysignf(1.f, tau) * frcp(fabsf(tau) + fsqrt(1.f + tau * tau));
  float c   = frsq(1.f + t * t);
  float s   = t * c;
  float cP[3], cQ[3];
  #pragma unroll
  for (int k = 0; k < 3; ++k) { cP[k] = c*A[k][P] - s*A[k][Q]; cQ[k] = s*A[k][P] + c*A[k][Q]; }
  #pragma unroll
  for (int k = 0; k < 3; ++k) { A[k][P] = cP[k]; A[k][Q] = cQ[k]; }
  float rP[3], rQ[3];
  #pragma unroll
  for (int k = 0; k < 3; ++k) { rP[k] = c*A[P][k] - s*A[Q][k]; rQ[k] = s*A[P][k] + c*A[Q][k]; }
  #pragma unroll
  for (int k = 0; k < 3; ++k) { A[P][k] = rP[k]; A[Q][k] = rQ[k]; }
  #pragma unroll
  for (int k = 0; k < 3; ++k) {
    float vp = c*Vv[k][P] - s*Vv[k][Q];
    Vv[k][Q] = s*Vv[k][P] + c*Vv[k][Q];
    Vv[k][P] = vp;
  }
}

#define CSWAP(I, J)                                                        \
  if (lam[I] < lam[J]) {                                                   \
    float tl = lam[I]; lam[I] = lam[J]; lam[J] = tl;                       \
    _Pragma("unroll")                                                      \
    for (int r = 0; r < 3; ++r) {                                          \
      float tv = Vv[r][I]; Vv[r][I] = Vv[r][J]; Vv[r][J] = tv;             \
    }                                                                      \
  }

__device__ float procrustes_err(const float4* __restrict__ P4,
                                const float4* __restrict__ G4, int b) {
  const float4* Pr = P4 + b * 18;   // (24,3) = 18 float4
  const float4* Gr = G4 + b * 24;   // (24,4) = 24 float4

  float sx0=0,sx1=0,sx2=0, sy0=0,sy1=0,sy2=0, sxx=0;
  float Ku[3][3] = {{0,0,0},{0,0,0},{0,0,0}};
  #pragma unroll
  for (int g = 0; g < 6; ++g) {
    float4 p0 = Pr[g*3+0], p1 = Pr[g*3+1], p2 = Pr[g*3+2];
    float px[4][3] = {{p0.x,p0.y,p0.z},{p0.w,p1.x,p1.y},
                      {p1.z,p1.w,p2.x},{p2.y,p2.z,p2.w}};
    #pragma unroll
    for (int q = 0; q < 4; ++q) {
      float4 gg = Gr[g*4+q];
      float x0 = px[q][0], x1 = px[q][1], x2 = px[q][2];
      sx0 += x0; sx1 += x1; sx2 += x2;
      sy0 += gg.x; sy1 += gg.y; sy2 += gg.z;
      sxx += x0*x0 + x1*x1 + x2*x2;
      Ku[0][0]+=x0*gg.x; Ku[0][1]+=x0*gg.y; Ku[0][2]+=x0*gg.z;
      Ku[1][0]+=x1*gg.x; Ku[1][1]+=x1*gg.y; Ku[1][2]+=x1*gg.z;
      Ku[2][0]+=x2*gg.x; Ku[2][1]+=x2*gg.y; Ku[2][2]+=x2*gg.z;
    }
  }
  const float inv24 = 1.f / 24.f;
  float mu1x=sx0*inv24, mu1y=sx1*inv24, mu1z=sx2*inv24;
  float mu2x=sy0*inv24, mu2y=sy1*inv24, mu2z=sy2*inv24;
  float m1v[3] = {mu1x, mu1y, mu1z};
  float m2v[3] = {mu2x, mu2y, mu2z};
  float K[3][3];
  #pragma unroll
  for (int r = 0; r < 3; ++r)
    #pragma unroll
    for (int c = 0; c < 3; ++c)
      K[r][c] = Ku[r][c] - 24.f * m1v[r] * m2v[c] + EPSF;
  float var1 = sxx - 24.f * (mu1x*mu1x + mu1y*mu1y + mu1z*mu1z);

  float detK = K[0][0]*(K[1][1]*K[2][2]-K[1][2]*K[2][1])
             - K[0][1]*(K[1][0]*K[2][2]-K[1][2]*K[2][0])
             + K[0][2]*(K[1][0]*K[2][1]-K[1][1]*K[2][0]);
  float sgn = (detK > 0.f) ? 1.f : ((detK < 0.f) ? -1.f : 0.f);

  float A[3][3];
  #pragma unroll
  for (int r = 0; r < 3; ++r)
    #pragma unroll
    for (int c = 0; c < 3; ++c)
      A[r][c] = K[0][r]*K[0][c] + K[1][r]*K[1][c] + K[2][r]*K[2][c];

  float Vv[3][3] = {{1,0,0},{0,1,0},{0,0,1}};
  for (int sweep = 0; sweep < 8; ++sweep) {
    jrot<0,1>(A, Vv); jrot<0,2>(A, Vv); jrot<1,2>(A, Vv);
  }
  float lam[3] = {A[0][0], A[1][1], A[2][2]};
  CSWAP(0,1) CSWAP(0,2) CSWAP(1,2)

  float Rm[3][3] = {{0,0,0},{0,0,0},{0,0,0}};
  float zi[3] = {1.f, 1.f, sgn};
  float trRK = 0.f;
  #pragma unroll
  for (int i = 0; i < 3; ++i) {
    float v0 = Vv[0][i], v1 = Vv[1][i], v2 = Vv[2][i];
    float a0 = K[0][0]*v0 + K[0][1]*v1 + K[0][2]*v2;
    float a1 = K[1][0]*v0 + K[1][1]*v1 + K[1][2]*v2;
    float a2 = K[2][0]*v0 + K[2][1]*v1 + K[2][2]*v2;
    float si = fsqrt(a0*a0 + a1*a1 + a2*a2);
    float zs = zi[i] * frcp(fmaxf(si, 1e-20f));
    Rm[0][0]+=zs*v0*a0; Rm[0][1]+=zs*v0*a1; Rm[0][2]+=zs*v0*a2;
    Rm[1][0]+=zs*v1*a0; Rm[1][1]+=zs*v1*a1; Rm[1][2]+=zs*v1*a2;
    Rm[2][0]+=zs*v2*a0; Rm[2][1]+=zs*v2*a1; Rm[2][2]+=zs*v2*a2;
    trRK += zi[i] * si;
  }
  float scale = trRK * frcp(var1);
  float t0 = mu2x - scale*(Rm[0][0]*mu1x + Rm[0][1]*mu1y + Rm[0][2]*mu1z);
  float t1 = mu2y - scale*(Rm[1][0]*mu1x + Rm[1][1]*mu1y + Rm[1][2]*mu1z);
  float t2 = mu2z - scale*(Rm[2][0]*mu1x + Rm[2][1]*mu1y + Rm[2][2]*mu1z);

  float errsum = 0.f;
  #pragma unroll
  for (int g = 0; g < 6; ++g) {
    float4 p0 = Pr[g*3+0], p1 = Pr[g*3+1], p2 = Pr[g*3+2];
    float px[4][3] = {{p0.x,p0.y,p0.z},{p0.w,p1.x,p1.y},
                      {p1.z,p1.w,p2.x},{p2.y,p2.z,p2.w}};
    #pragma unroll
    for (int q = 0; q < 4; ++q) {
      float4 gg = Gr[g*4+q];
      float X = px[q][0], Y = px[q][1], Z = px[q][2];
      float q0 = scale*(Rm[0][0]*X + Rm[0][1]*Y + Rm[0][2]*Z) + t0;
      float q1 = scale*(Rm[1][0]*X + Rm[1][1]*Y + Rm[1][2]*Z) + t1;
      float q2 = scale*(Rm[2][0]*X + Rm[2][1]*Y + Rm[2][2]*Z) + t2;
      float d0 = q0 - gg.x, d1 = q1 - gg.y, d2 = q2 - gg.z;
      errsum += fsqrt(d0*d0 + d1*d1 + d2*d2);
    }
  }
  return errsum;
}

// ---------------- fused kernel: 64-VGPR cap (8 waves/EU = 32 waves/CU).
// Procrustes path may spill to scratch (8 blocks only; hidden under stream).
__global__ __launch_bounds__(256, 8) void bmp_all(
    const float4* __restrict__ pred_rot4,   const float* __restrict__ pred_camera,
    const float*  __restrict__ pred_joints, const float4* __restrict__ pred_verts,
    const float*  __restrict__ pred_betas,  const float4* __restrict__ gt_rot4,
    const float*  __restrict__ gt_shape,    const float* __restrict__ gt_kp2d,
    const float*  __restrict__ gt_kp3d,     const float4* __restrict__ gt_verts,
    const int*    __restrict__ has_smpl,    double* __restrict__ ws) {
  const int bid = blockIdx.x;
  const int tid = threadIdx.x;

  if (bid >= NSIDE) {                        // ---- vertex |diff| stream ----
    const int chunk  = bid - NSIDE;          // 0..1291
    const int f4base = chunk * 2048;
    const int nf4    = min(2048, NV4 - f4base);      // 2048 or 1792
    const int e0     = f4base * 4;
    const int b0     = e0 / PER_B;
    const int blast  = (e0 + nf4 * 4 - 1) / PER_B;   // b0 or b0+1
    const int m0     = has_smpl[b0] > 0;
    const int m1     = has_smpl[blast] > 0;
    float acc = 0.f;
    if (m0 | m1) {
      const float4* __restrict__ P = pred_verts + f4base + tid;
      const float4* __restrict__ G = gt_verts  + f4base + tid;
      if (nf4 == 2048) {
        if (m0 & m1) {
          #pragma unroll
          for (int h = 0; h < 2; ++h) {              // 2 half-batches: caps VGPR
            float4 pa[4], ga[4];
            #pragma unroll
            for (int k = 0; k < 4; ++k) pa[k] = P[(h * 4 + k) * 256];
            #pragma unroll
            for (int k = 0; k < 4; ++k) ga[k] = G[(h * 4 + k) * 256];
            #pragma unroll
            for (int k = 0; k < 4; ++k)
              acc += fabsf(pa[k].x-ga[k].x) + fabsf(pa[k].y-ga[k].y)
                   + fabsf(pa[k].z-ga[k].z) + fabsf(pa[k].w-ga[k].w);
          }
        } else {                                     // batch boundary inside chunk
          const int   bnd = (b0 + 1) * PER_B;
          const float fm0 = m0 ? 1.f : 0.f;
          const float fm1 = m1 ? 1.f : 0.f;
          #pragma unroll
          for (int h = 0; h < 2; ++h) {
            float4 pa[4], ga[4];
            #pragma unroll
            for (int k = 0; k < 4; ++k) pa[k] = P[(h * 4 + k) * 256];
            #pragma unroll
            for (int k = 0; k < 4; ++k) ga[k] = G[(h * 4 + k) * 256];
            #pragma unroll
            for (int k = 0; k < 4; ++k) {
              int e = (f4base + tid + (h * 4 + k) * 256) * 4;
              acc += ((e+0) >= bnd ? fm1 : fm0) * fabsf(pa[k].x-ga[k].x)
                   + ((e+1) >= bnd ? fm1 : fm0) * fabsf(pa[k].y-ga[k].y)
                   + ((e+2) >= bnd ? fm1 : fm0) * fabsf(pa[k].z-ga[k].z)
                   + ((e+3) >= bnd ? fm1 : fm0) * fabsf(pa[k].w-ga[k].w);
            }
          }
        }
      } else {                                       // last chunk: 7*256, one batch
        #pragma unroll
        for (int k = 0; k < 7; ++k) {
          float4 a = P[k * 256], b = G[k * 256];
          acc += fabsf(a.x-b.x) + fabsf(a.y-b.y) + fabsf(a.z-b.z) + fabsf(a.w-b.w);
        }
      }
    }
    block_sum_store(acc, &ws[bid]);
    return;
  }

  if (bid >= S_POSE) {                       // ---- pose: mask*(dR)^2, float4 ----
    int idx = (bid - S_POSE) * 256 + tid;    // < 27648
    int b   = idx / 54;
    float m = (has_smpl[b] > 0) ? 1.f : 0.f;
    float4 p = pred_rot4[idx], g = gt_rot4[idx];
    float dx = p.x-g.x, dy = p.y-g.y, dz = p.z-g.z, dw = p.w-g.w;
    block_sum_store(m * (dx*dx + dy*dy + dz*dz + dw*dw), &ws[bid]);
    return;
  }
  if (bid >= S_KP3D) {                       // ---- kp3d ----
    int idx = (bid - S_KP3D) * 256 + tid;    // < 12288
    int b = idx / 24, j = idx - (idx / 24) * 24;
    const float* PJ = pred_joints + b * 72;
    const float* G  = gt_kp3d + b * 96;
    float cf = G[j*4+3];
    float ssum = 0.f;
    #pragma unroll
    for (int c = 0; c < 3; ++c) {
      float prp = 0.5f * (PJ[2*3+c] + PJ[3*3+c]);
      float gtp = 0.5f * (G[2*4+c] + G[3*4+c]);
      ssum += fabsf((PJ[j*3+c] - prp) - (G[j*4+c] - gtp));
    }
    block_sum_store(cf * ssum, &ws[bid]);
    return;
  }
  if (bid >= S_KP2D) {                       // ---- kp2d ----
    int idx = (bid - S_KP2D) * 256 + tid;    // < 12288
    int b = idx / 24, j = idx - (idx / 24) * 24;
    float cam0 = pred_camera[b*3+0], cam1 = pred_camera[b*3+1], cam2 = pred_camera[b*3+2];
    float depth = 2.f * 1000.f / (EPSF + cam0 * 512.f);
    float px = pred_joints[(b*24+j)*3+0] + cam1;
    float py = pred_joints[(b*24+j)*3+1] + cam2;
    float pz = pred_joints[(b*24+j)*3+2] + depth;
    float kxn = (1000.f * px / pz + 256.f) * (1.f / 512.f);
    float kyn = (1000.f * py / pz + 256.f) * (1.f / 512.f);
    float gx = gt_kp2d[(b*24+j)*3+0] * (1.f / 512.f);
    float gy = gt_kp2d[(b*24+j)*3+1] * (1.f / 512.f);
    float cf = gt_kp2d[(b*24+j)*3+2];
    block_sum_store(cf * (fabsf(kxn - gx) + fabsf(kyn - gy)), &ws[bid]);
    return;
  }
  if (bid >= S_BETA) {                       // ---- betas ----
    int idx = (bid - S_BETA) * 256 + tid;    // < 5120
    int b = idx / 10;
    float m = (has_smpl[b] > 0) ? 1.f : 0.f;
    float d = pred_betas[idx] - gt_shape[idx];
    block_sum_store(m * d * d, &ws[bid]);
    return;
  }
  if (bid >= S_NV) {                         // ---- n_valid ----
    int idx = (bid - S_NV) * 256 + tid;      // < 512
    block_sum_store((has_smpl[idx] > 0) ? 1.f : 0.f, &ws[bid]);
    return;
  }
  {                                          // ---- Procrustes (8 blocks) ----
    float e = 0.f;
    if (tid < 64) {
      int b = bid * 64 + tid;                // < 512
      e = procrustes_err((const float4*)pred_joints, (const float4*)gt_kp3d, b);
    }
    block_sum_store(e, &ws[bid]);
  }
}

// ---------------- finalize ----------------
__global__ __launch_bounds__(256) void bmp_finalize(const double* __restrict__ ws,
                                                    float* __restrict__ out) {
  const int tid = threadIdx.x;
  double s[7] = {0,0,0,0,0,0,0};
  for (int i = tid; i < NBLK; i += 256) {
    double v = ws[i];
    int slot;
    if (i >= NSIDE)        slot = 0;         // shape
    else if (i >= S_POSE)  slot = 1;         // pose
    else if (i >= S_KP3D)  slot = 2;         // kp3d
    else if (i >= S_KP2D)  slot = 3;         // kp2d
    else if (i >= S_BETA)  slot = 4;         // betas
    else if (i >= S_NV)    slot = 5;         // nvalid
    else                   slot = 6;         // pa
    s[slot] += v;
  }
  #pragma unroll
  for (int k = 0; k < 7; ++k)
    #pragma unroll
    for (int off = 32; off > 0; off >>= 1) s[k] += __shfl_down(s[k], off);
  __shared__ double red[4][7];
  const int lane = tid & 63, wid = tid >> 6;
  if (lane == 0)
    #pragma unroll
    for (int k = 0; k < 7; ++k) red[wid][k] = s[k];
  __syncthreads();
  if (tid == 0) {
    double t[7];
    #pragma unroll
    for (int k = 0; k < 7; ++k) t[k] = red[0][k]+red[1][k]+red[2][k]+red[3][k];
    double nv = t[5];
    double loss_kp2d  = t[3] / 24576.0;              // 512*24*2
    double loss_kp3d  = t[2] / 36864.0;              // 512*24*3
    double loss_shape = t[0] / (nv * 20670.0 + 1e-8);
    double loss_pose  = t[1] / (nv * 216.0   + 1e-8);
    double loss_betas = t[4] / (nv * 10.0    + 1e-8);
    double pa         = t[6] / 12288.0;              // 512*24
    out[0] = (float)(4.0*loss_kp2d + 4.0*loss_kp3d + loss_shape + loss_pose
                     + 0.01*loss_betas + pa);
  }
}

extern "C" void kernel_launch(void* const* d_in, const int* in_sizes, int n_in,
                              void* d_out, int out_size, void* d_ws, size_t ws_size,
                              hipStream_t stream) {
  const float4* pred_rot4   = (const float4*)d_in[0];
  const float*  pred_camera = (const float*)d_in[1];
  const float*  pred_joints = (const float*)d_in[2];
  const float4* pred_verts  = (const float4*)d_in[3];
  const float*  pred_betas  = (const float*)d_in[4];
  const float4* gt_rot4     = (const float4*)d_in[5];
  const float*  gt_shape    = (const float*)d_in[6];
  const float*  gt_kp2d     = (const float*)d_in[7];
  const float*  gt_kp3d     = (const float*)d_in[8];
  const float4* gt_verts    = (const float4*)d_in[9];
  const int*    has_smpl    = (const int*)d_in[10];
  double* ws = (double*)d_ws;

  bmp_all<<<NBLK, 256, 0, stream>>>(pred_rot4, pred_camera, pred_joints,
      pred_verts, pred_betas, gt_rot4, gt_shape, gt_kp2d, gt_kp3d, gt_verts,
      has_smpl, ws);
  bmp_finalize<<<1, 256, 0, stream>>>(ws, (float*)d_out);
}

// Round 7
// 127.437 us; speedup vs baseline: 1.1993x; 1.1993x over previous
//
#include <hip/hip_runtime.h>
#include <math.h>

#define EPSF   1e-8f
#define NV4    2645760   // 512*6890*3 / 4
#define PER_B  20670     // 6890*3

// block-role layout. ws[bid] = this block's partial (double). No atomics, no init.
#define B_PROC   0      // 8 blocks, 64 active threads each -> 512 batches
#define B_NV     8      // 2 blocks
#define B_BETA   10     // 20 blocks (5120)
#define B_KP2D   30     // 48 blocks (12288)
#define B_KP3D   78     // 48 blocks (12288)
#define B_POSE   126    // 108 blocks (27648 float4)
#define B_VERT   234    // 1292 blocks (2048 float4 chunks)
#define NBLK     1526

__device__ __forceinline__ float frcp(float x)  { return __builtin_amdgcn_rcpf(x); }
__device__ __forceinline__ float frsq(float x)  { return __builtin_amdgcn_rsqf(x); }
__device__ __forceinline__ float fsqrt(float x) { return __builtin_amdgcn_sqrtf(x); }

__device__ __forceinline__ void block_sum_store(float v, double* dst) {
  #pragma unroll
  for (int off = 32; off > 0; off >>= 1) v += __shfl_down(v, off);
  __shared__ float red[4];
  const int lane = threadIdx.x & 63;
  const int wid  = threadIdx.x >> 6;
  if (lane == 0) red[wid] = v;
  __syncthreads();
  if (threadIdx.x == 0) *dst = (double)(red[0] + red[1] + red[2] + red[3]);
}

// one Jacobi rotation on symmetric A zeroing A[P][Q]; accumulates V <- V*J
template<int P, int Q>
__device__ __forceinline__ void jrot(float A[3][3], float Vv[3][3]) {
  float apq = A[P][Q];
  if (fabsf(apq) < 1e-20f) return;
  float tau = (A[Q][Q] - A[P][P]) * 0.5f * frcp(apq);
  float t   = copysignf(1.f, tau) * frcp(fabsf(tau) + fsqrt(1.f + tau * tau));
  float c   = frsq(1.f + t * t);
  float s   = t * c;
  float cP[3], cQ[3];
  #pragma unroll
  for (int k = 0; k < 3; ++k) { cP[k] = c*A[k][P] - s*A[k][Q]; cQ[k] = s*A[k][P] + c*A[k][Q]; }
  #pragma unroll
  for (int k = 0; k < 3; ++k) { A[k][P] = cP[k]; A[k][Q] = cQ[k]; }
  float rP[3], rQ[3];
  #pragma unroll
  for (int k = 0; k < 3; ++k) { rP[k] = c*A[P][k] - s*A[Q][k]; rQ[k] = s*A[P][k] + c*A[Q][k]; }
  #pragma unroll
  for (int k = 0; k < 3; ++k) { A[P][k] = rP[k]; A[Q][k] = rQ[k]; }
  #pragma unroll
  for (int k = 0; k < 3; ++k) {
    float vp = c*Vv[k][P] - s*Vv[k][Q];
    Vv[k][Q] = s*Vv[k][P] + c*Vv[k][Q];
    Vv[k][P] = vp;
  }
}

#define CSWAP(I, J)                                                        \
  if (lam[I] < lam[J]) {                                                   \
    float tl = lam[I]; lam[I] = lam[J]; lam[J] = tl;                       \
    _Pragma("unroll")                                                      \
    for (int r = 0; r < 3; ++r) {                                          \
      float tv = Vv[r][I]; Vv[r][I] = Vv[r][J]; Vv[r][J] = tv;             \
    }                                                                      \
  }

// per-batch Procrustes via float4 gathers; single-pass moments, re-load for error
__device__ float procrustes_err(const float4* __restrict__ P4,
                                const float4* __restrict__ G4, int b) {
  const float4* Pr = P4 + b * 18;   // 24 joints * 3 = 18 float4
  const float4* Gr = G4 + b * 24;   // 24 joints * 4 = 24 float4

  float sx0=0,sx1=0,sx2=0, sy0=0,sy1=0,sy2=0, sxx=0;
  float Ku[3][3] = {{0,0,0},{0,0,0},{0,0,0}};
  #pragma unroll
  for (int g = 0; g < 6; ++g) {
    float4 p0 = Pr[g*3+0], p1 = Pr[g*3+1], p2 = Pr[g*3+2];
    float px[4][3] = {{p0.x,p0.y,p0.z},{p0.w,p1.x,p1.y},
                      {p1.z,p1.w,p2.x},{p2.y,p2.z,p2.w}};
    #pragma unroll
    for (int q = 0; q < 4; ++q) {
      float4 gg = Gr[g*4+q];
      float x0 = px[q][0], x1 = px[q][1], x2 = px[q][2];
      sx0 += x0; sx1 += x1; sx2 += x2;
      sy0 += gg.x; sy1 += gg.y; sy2 += gg.z;
      sxx += x0*x0 + x1*x1 + x2*x2;
      Ku[0][0]+=x0*gg.x; Ku[0][1]+=x0*gg.y; Ku[0][2]+=x0*gg.z;
      Ku[1][0]+=x1*gg.x; Ku[1][1]+=x1*gg.y; Ku[1][2]+=x1*gg.z;
      Ku[2][0]+=x2*gg.x; Ku[2][1]+=x2*gg.y; Ku[2][2]+=x2*gg.z;
    }
  }
  const float inv24 = 1.f / 24.f;
  float mu1x=sx0*inv24, mu1y=sx1*inv24, mu1z=sx2*inv24;
  float mu2x=sy0*inv24, mu2y=sy1*inv24, mu2z=sy2*inv24;
  float m1v[3] = {mu1x, mu1y, mu1z};
  float m2v[3] = {mu2x, mu2y, mu2z};
  float K[3][3];
  #pragma unroll
  for (int r = 0; r < 3; ++r)
    #pragma unroll
    for (int c = 0; c < 3; ++c)
      K[r][c] = Ku[r][c] - 24.f * m1v[r] * m2v[c] + EPSF;
  float var1 = sxx - 24.f * (mu1x*mu1x + mu1y*mu1y + mu1z*mu1z);

  float detK = K[0][0]*(K[1][1]*K[2][2]-K[1][2]*K[2][1])
             - K[0][1]*(K[1][0]*K[2][2]-K[1][2]*K[2][0])
             + K[0][2]*(K[1][0]*K[2][1]-K[1][1]*K[2][0]);
  float sgn = (detK > 0.f) ? 1.f : ((detK < 0.f) ? -1.f : 0.f);

  float A[3][3];
  #pragma unroll
  for (int r = 0; r < 3; ++r)
    #pragma unroll
    for (int c = 0; c < 3; ++c)
      A[r][c] = K[0][r]*K[0][c] + K[1][r]*K[1][c] + K[2][r]*K[2][c];

  float Vv[3][3] = {{1,0,0},{0,1,0},{0,0,1}};
  for (int sweep = 0; sweep < 8; ++sweep) {
    jrot<0,1>(A, Vv); jrot<0,2>(A, Vv); jrot<1,2>(A, Vv);
  }
  float lam[3] = {A[0][0], A[1][1], A[2][2]};
  CSWAP(0,1) CSWAP(0,2) CSWAP(1,2)

  float Rm[3][3] = {{0,0,0},{0,0,0},{0,0,0}};
  float zi[3] = {1.f, 1.f, sgn};
  float trRK = 0.f;
  #pragma unroll
  for (int i = 0; i < 3; ++i) {
    float v0 = Vv[0][i], v1 = Vv[1][i], v2 = Vv[2][i];
    float a0 = K[0][0]*v0 + K[0][1]*v1 + K[0][2]*v2;
    float a1 = K[1][0]*v0 + K[1][1]*v1 + K[1][2]*v2;
    float a2 = K[2][0]*v0 + K[2][1]*v1 + K[2][2]*v2;
    float si = fsqrt(a0*a0 + a1*a1 + a2*a2);
    float zs = zi[i] * frcp(fmaxf(si, 1e-20f));
    Rm[0][0]+=zs*v0*a0; Rm[0][1]+=zs*v0*a1; Rm[0][2]+=zs*v0*a2;
    Rm[1][0]+=zs*v1*a0; Rm[1][1]+=zs*v1*a1; Rm[1][2]+=zs*v1*a2;
    Rm[2][0]+=zs*v2*a0; Rm[2][1]+=zs*v2*a1; Rm[2][2]+=zs*v2*a2;
    trRK += zi[i] * si;
  }
  float scale = trRK * frcp(var1);
  float t0 = mu2x - scale*(Rm[0][0]*mu1x + Rm[0][1]*mu1y + Rm[0][2]*mu1z);
  float t1 = mu2y - scale*(Rm[1][0]*mu1x + Rm[1][1]*mu1y + Rm[1][2]*mu1z);
  float t2 = mu2z - scale*(Rm[2][0]*mu1x + Rm[2][1]*mu1y + Rm[2][2]*mu1z);

  float errsum = 0.f;
  #pragma unroll
  for (int g = 0; g < 6; ++g) {
    float4 p0 = Pr[g*3+0], p1 = Pr[g*3+1], p2 = Pr[g*3+2];
    float px[4][3] = {{p0.x,p0.y,p0.z},{p0.w,p1.x,p1.y},
                      {p1.z,p1.w,p2.x},{p2.y,p2.z,p2.w}};
    #pragma unroll
    for (int q = 0; q < 4; ++q) {
      float4 gg = Gr[g*4+q];
      float X = px[q][0], Y = px[q][1], Z = px[q][2];
      float q0 = scale*(Rm[0][0]*X + Rm[0][1]*Y + Rm[0][2]*Z) + t0;
      float q1 = scale*(Rm[1][0]*X + Rm[1][1]*Y + Rm[1][2]*Z) + t1;
      float q2 = scale*(Rm[2][0]*X + Rm[2][1]*Y + Rm[2][2]*Z) + t2;
      float d0 = q0 - gg.x, d1 = q1 - gg.y, d2 = q2 - gg.z;
      errsum += fsqrt(d0*d0 + d1*d1 + d2*d2);
    }
  }
  return errsum;
}

__global__ __launch_bounds__(256) void bmp_main(
    const float4* __restrict__ pred_rot4,   const float* __restrict__ pred_camera,
    const float*  __restrict__ pred_joints, const float4* __restrict__ pred_verts,
    const float*  __restrict__ pred_betas,  const float4* __restrict__ gt_rot4,
    const float*  __restrict__ gt_shape,    const float* __restrict__ gt_kp2d,
    const float*  __restrict__ gt_kp3d,     const float4* __restrict__ gt_verts,
    const int*    __restrict__ has_smpl,    double* __restrict__ ws) {
  const int bid = blockIdx.x;
  const int tid = threadIdx.x;

  if (bid >= B_VERT) {                       // ---- vertex |diff| stream ----
    const int chunk  = bid - B_VERT;         // 0..1291
    const int f4base = chunk * 2048;
    const int nf4    = min(2048, NV4 - f4base);  // 2048 or 1792 (=7*256)
    const int e0     = f4base * 4;
    const int b0     = e0 / PER_B;
    const int blast  = (e0 + nf4 * 4 - 1) / PER_B;   // b0 or b0+1
    const int m0     = has_smpl[b0] > 0;
    const int m1     = has_smpl[blast] > 0;
    float acc = 0.f;
    if (m0 | m1) {
      const float4* __restrict__ P = pred_verts + f4base + tid;
      const float4* __restrict__ G = gt_verts  + f4base + tid;
      if (nf4 == 2048) {
        float4 pa[8], ga[8];
        #pragma unroll
        for (int k = 0; k < 8; ++k) pa[k] = P[k * 256];
        #pragma unroll
        for (int k = 0; k < 8; ++k) ga[k] = G[k * 256];
        if (m0 & m1) {
          #pragma unroll
          for (int k = 0; k < 8; ++k)
            acc += fabsf(pa[k].x-ga[k].x) + fabsf(pa[k].y-ga[k].y)
                 + fabsf(pa[k].z-ga[k].z) + fabsf(pa[k].w-ga[k].w);
        } else {                             // one side of boundary masked out
          const int   bnd = (b0 + 1) * PER_B;
          const float fm0 = m0 ? 1.f : 0.f;
          const float fm1 = m1 ? 1.f : 0.f;
          #pragma unroll
          for (int k = 0; k < 8; ++k) {
            int e = (f4base + tid + k * 256) * 4;
            acc += ((e+0) >= bnd ? fm1 : fm0) * fabsf(pa[k].x-ga[k].x)
                 + ((e+1) >= bnd ? fm1 : fm0) * fabsf(pa[k].y-ga[k].y)
                 + ((e+2) >= bnd ? fm1 : fm0) * fabsf(pa[k].z-ga[k].z)
                 + ((e+3) >= bnd ? fm1 : fm0) * fabsf(pa[k].w-ga[k].w);
          }
        }
      } else {                               // last chunk: single batch, m0 set
        #pragma unroll
        for (int k = 0; k < 7; ++k) {
          float4 a = P[k * 256], b = G[k * 256];
          acc += fabsf(a.x-b.x) + fabsf(a.y-b.y) + fabsf(a.z-b.z) + fabsf(a.w-b.w);
        }
      }
    }
    block_sum_store(acc, &ws[bid]);
    return;
  }

  if (bid >= B_POSE) {                       // ---- pose: mask*(dR)^2, float4 ----
    int idx = (bid - B_POSE) * 256 + tid;    // < 27648
    int b   = idx / 54;                      // 216 floats = 54 float4 per batch
    float m = (has_smpl[b] > 0) ? 1.f : 0.f;
    float4 p = pred_rot4[idx], g = gt_rot4[idx];
    float dx = p.x-g.x, dy = p.y-g.y, dz = p.z-g.z, dw = p.w-g.w;
    block_sum_store(m * (dx*dx + dy*dy + dz*dz + dw*dw), &ws[bid]);
    return;
  }

  if (bid >= B_KP3D) {                       // ---- kp3d ----
    int idx = (bid - B_KP3D) * 256 + tid;    // < 12288
    int b = idx / 24, j = idx - (idx / 24) * 24;
    const float* PJ = pred_joints + b * 72;
    const float* G  = gt_kp3d + b * 96;
    float cf = G[j*4+3];
    float ssum = 0.f;
    #pragma unroll
    for (int c = 0; c < 3; ++c) {
      float prp = 0.5f * (PJ[2*3+c] + PJ[3*3+c]);
      float gtp = 0.5f * (G[2*4+c] + G[3*4+c]);
      ssum += fabsf((PJ[j*3+c] - prp) - (G[j*4+c] - gtp));
    }
    block_sum_store(cf * ssum, &ws[bid]);
    return;
  }

  if (bid >= B_KP2D) {                       // ---- kp2d ----
    int idx = (bid - B_KP2D) * 256 + tid;    // < 12288
    int b = idx / 24, j = idx - (idx / 24) * 24;
    float cam0 = pred_camera[b*3+0], cam1 = pred_camera[b*3+1], cam2 = pred_camera[b*3+2];
    float depth = 2.f * 1000.f / (EPSF + cam0 * 512.f);
    float px = pred_joints[(b*24+j)*3+0] + cam1;
    float py = pred_joints[(b*24+j)*3+1] + cam2;
    float pz = pred_joints[(b*24+j)*3+2] + depth;
    float kxn = (1000.f * px / pz + 256.f) * (1.f / 512.f);
    float kyn = (1000.f * py / pz + 256.f) * (1.f / 512.f);
    float gx = gt_kp2d[(b*24+j)*3+0] * (1.f / 512.f);
    float gy = gt_kp2d[(b*24+j)*3+1] * (1.f / 512.f);
    float cf = gt_kp2d[(b*24+j)*3+2];
    block_sum_store(cf * (fabsf(kxn - gx) + fabsf(kyn - gy)), &ws[bid]);
    return;
  }

  if (bid >= B_BETA) {                       // ---- betas ----
    int idx = (bid - B_BETA) * 256 + tid;    // < 5120
    int b = idx / 10;
    float m = (has_smpl[b] > 0) ? 1.f : 0.f;
    float d = pred_betas[idx] - gt_shape[idx];
    block_sum_store(m * d * d, &ws[bid]);
    return;
  }

  if (bid >= B_NV) {                         // ---- n_valid ----
    int idx = (bid - B_NV) * 256 + tid;      // < 512
    block_sum_store((has_smpl[idx] > 0) ? 1.f : 0.f, &ws[bid]);
    return;
  }

  {                                          // ---- Procrustes (8 blocks) ----
    float e = 0.f;
    if (tid < 64) {
      int b = bid * 64 + tid;                // < 512
      e = procrustes_err((const float4*)pred_joints, (const float4*)gt_kp3d, b);
    }
    block_sum_store(e, &ws[bid]);
  }
}

__global__ __launch_bounds__(256) void bmp_finalize(const double* __restrict__ ws,
                                                    float* __restrict__ out) {
  const int tid = threadIdx.x;
  double s[7] = {0,0,0,0,0,0,0};
  for (int i = tid; i < NBLK; i += 256) {
    double v = ws[i];
    int slot;
    if      (i >= B_VERT) slot = 0;   // shape
    else if (i >= B_POSE) slot = 1;   // pose
    else if (i >= B_KP3D) slot = 2;   // kp3d
    else if (i >= B_KP2D) slot = 3;   // kp2d
    else if (i >= B_BETA) slot = 4;   // betas
    else if (i >= B_NV)   slot = 5;   // nvalid
    else                  slot = 6;   // pa
    s[slot] += v;
  }
  #pragma unroll
  for (int k = 0; k < 7; ++k)
    #pragma unroll
    for (int off = 32; off > 0; off >>= 1) s[k] += __shfl_down(s[k], off);
  __shared__ double red[4][7];
  const int lane = tid & 63, wid = tid >> 6;
  if (lane == 0)
    #pragma unroll
    for (int k = 0; k < 7; ++k) red[wid][k] = s[k];
  __syncthreads();
  if (tid == 0) {
    double t[7];
    #pragma unroll
    for (int k = 0; k < 7; ++k) t[k] = red[0][k]+red[1][k]+red[2][k]+red[3][k];
    double nv = t[5];
    double loss_kp2d  = t[3] / 24576.0;              // 512*24*2
    double loss_kp3d  = t[2] / 36864.0;              // 512*24*3
    double loss_shape = t[0] / (nv * 20670.0 + 1e-8);
    double loss_pose  = t[1] / (nv * 216.0   + 1e-8);
    double loss_betas = t[4] / (nv * 10.0    + 1e-8);
    double pa         = t[6] / 12288.0;              // 512*24
    out[0] = (float)(4.0*loss_kp2d + 4.0*loss_kp3d + loss_shape + loss_pose
                     + 0.01*loss_betas + pa);
  }
}

extern "C" void kernel_launch(void* const* d_in, const int* in_sizes, int n_in,
                              void* d_out, int out_size, void* d_ws, size_t ws_size,
                              hipStream_t stream) {
  const float4* pred_rot4   = (const float4*)d_in[0];
  const float*  pred_camera = (const float*)d_in[1];
  const float*  pred_joints = (const float*)d_in[2];
  const float4* pred_verts  = (const float4*)d_in[3];
  const float*  pred_betas  = (const float*)d_in[4];
  const float4* gt_rot4     = (const float4*)d_in[5];
  const float*  gt_shape    = (const float*)d_in[6];
  const float*  gt_kp2d     = (const float*)d_in[7];
  const float*  gt_kp3d     = (const float*)d_in[8];
  const float4* gt_verts    = (const float4*)d_in[9];
  const int*    has_smpl    = (const int*)d_in[10];
  double* ws = (double*)d_ws;

  bmp_main<<<NBLK, 256, 0, stream>>>(pred_rot4, pred_camera, pred_joints,
      pred_verts, pred_betas, gt_rot4, gt_shape, gt_kp2d, gt_kp3d, gt_verts,
      has_smpl, ws);
  bmp_finalize<<<1, 256, 0, stream>>>(ws, (float*)d_out);
}